// Round 9
// baseline (112.976 us; speedup 1.0000x reference)
//
#include <hip/hip_runtime.h>
#include <hip/hip_bf16.h>

#define DM 2048
#define BB 64
#define SS 32
#define CC 8
#define KP 16   // k-split (gemm grid-units per e-block)
#define KR 128  // k-range per unit
#define NBLK 256

typedef __attribute__((ext_vector_type(8))) short short8;
typedef __attribute__((ext_vector_type(4))) short short4v;
typedef __attribute__((ext_vector_type(4))) float f32x4;

static __device__ __forceinline__ short f2bf(float f) {
  union { __hip_bfloat16 h; short s; } u;
  u.h = __float2bfloat16(f);
  return u.s;
}
static __device__ __forceinline__ float bf2f(short s) {
  union { float f; unsigned u; } u;
  u.u = ((unsigned)(unsigned short)s) << 16;
  return u.f;
}

// Grid barrier: monotonic counter (zeroed each launch by hipMemsetAsync).
// Release: agent fence (wbL2) before arrive; acquire load while spinning
// (invL1/L2). Deterministic replays make any stale line value-identical.
static __device__ __forceinline__ void gridbar(int* bar, int tgt) {
  __syncthreads();
  if (threadIdx.x == 0) {
    __threadfence();
    __hip_atomic_fetch_add(bar, 1, __ATOMIC_RELEASE, __HIP_MEMORY_SCOPE_AGENT);
    while (__hip_atomic_load(bar, __ATOMIC_ACQUIRE,
                             __HIP_MEMORY_SCOPE_AGENT) < tgt) {
      __builtin_amdgcn_s_sleep(1);
    }
  }
  __syncthreads();
}

// One r8-proven GEMM unit: part[kp][b][e](bf16) += A[b][k-slice]*W[e][k-slice]
// unit -> eblk = unit&31 (64 e), kp = unit>>5. Wave wv owns 16 e-rows.
// W staged via global_load_lds (swizzled global source, linear LDS dest),
// A fragments to regs, one vmcnt(0), 4x (2 ds_read_b128 + cvt + 4 MFMA).
static __device__ __forceinline__ void gemm_unit(
    const short* __restrict__ abf, const float* __restrict__ w,
    short* __restrict__ part, int unit, float* lds) {
  const int t    = threadIdx.x;
  const int lane = t & 63;
  const int wv   = t >> 6;
  float* ldsw    = lds + wv * (16 * 128);
  const int e0   = (unit & 31) * 64 + wv * 16;
  const int kp   = unit >> 5;
  const int k0   = kp * KR;

  const int rl = lane >> 5;
  const int g  = lane & 31;
#pragma unroll
  for (int i = 0; i < 8; ++i) {
    const int rr = 2 * i + rl;
    const float* src = w + (size_t)(e0 + rr) * DM + k0 + ((g ^ (rr & 7)) << 2);
    __builtin_amdgcn_global_load_lds(
        (const __attribute__((address_space(1))) void*)src,
        (__attribute__((address_space(3))) void*)(ldsw + i * 256), 16, 0, 0);
  }

  const int r  = lane & 15;
  const int kc = (lane >> 4) * 8;
  const short* ap = abf + (size_t)r * DM + k0 + kc;
  short8 a0[4], a1[4], a2[4], a3[4];
#pragma unroll
  for (int s = 0; s < 4; ++s) {
    const int ko = s * 32;
    a0[s] = *reinterpret_cast<const short8*>(ap + ko);
    a1[s] = *reinterpret_cast<const short8*>(ap + (size_t)16 * DM + ko);
    a2[s] = *reinterpret_cast<const short8*>(ap + (size_t)32 * DM + ko);
    a3[s] = *reinterpret_cast<const short8*>(ap + (size_t)48 * DM + ko);
  }

  asm volatile("s_waitcnt vmcnt(0)" ::: "memory");
  __builtin_amdgcn_sched_barrier(0);

  f32x4 acc0 = {0.f, 0.f, 0.f, 0.f}, acc1 = {0.f, 0.f, 0.f, 0.f};
  f32x4 acc2 = {0.f, 0.f, 0.f, 0.f}, acc3 = {0.f, 0.f, 0.f, 0.f};
  const float* lwr = ldsw + r * 128;
  const int q = r & 7;
#pragma unroll
  for (int s = 0; s < 4; ++s) {
    const int g0 = (lane >> 4) * 2 + s * 8;
    const float4 lo = *reinterpret_cast<const float4*>(lwr + ((g0 ^ q) << 2));
    const float4 hi =
        *reinterpret_cast<const float4*>(lwr + (((g0 + 1) ^ q) << 2));
    short8 bfrag;
    bfrag[0] = f2bf(lo.x); bfrag[1] = f2bf(lo.y);
    bfrag[2] = f2bf(lo.z); bfrag[3] = f2bf(lo.w);
    bfrag[4] = f2bf(hi.x); bfrag[5] = f2bf(hi.y);
    bfrag[6] = f2bf(hi.z); bfrag[7] = f2bf(hi.w);
    acc0 = __builtin_amdgcn_mfma_f32_16x16x32_bf16(a0[s], bfrag, acc0, 0, 0, 0);
    acc1 = __builtin_amdgcn_mfma_f32_16x16x32_bf16(a1[s], bfrag, acc1, 0, 0, 0);
    acc2 = __builtin_amdgcn_mfma_f32_16x16x32_bf16(a2[s], bfrag, acc2, 0, 0, 0);
    acc3 = __builtin_amdgcn_mfma_f32_16x16x32_bf16(a3[s], bfrag, acc3, 0, 0, 0);
  }

  const int brow = (lane >> 4) * 4;
  short* pb = part + ((size_t)kp * BB) * DM + e0 + r;
#pragma unroll
  for (int j = 0; j < 4; ++j) {
    pb[(size_t)(brow + j) * DM]      = f2bf(acc0[j]);
    pb[(size_t)(brow + j + 16) * DM] = f2bf(acc1[j]);
    pb[(size_t)(brow + j + 32) * DM] = f2bf(acc2[j]);
    pb[(size_t)(brow + j + 48) * DM] = f2bf(acc3[j]);
  }
}

// All 5 phases in one kernel; grid = 256 blocks x 256 thr (1+/CU resident).
__global__ __launch_bounds__(256, 1) void fused_all(
    const float* __restrict__ seq, const float* __restrict__ controls,
    const float* __restrict__ Wv, const float* __restrict__ bv,
    const float* __restrict__ Wo, const float* __restrict__ bo,
    short* __restrict__ u16, short* __restrict__ v16,
    short* __restrict__ part1, short* __restrict__ part2,
    float* __restrict__ out, int* __restrict__ bar) {
  __shared__ float lw[4][16][128];  // 32 KB, reused by both gemm phases
  const int bid = blockIdx.x;
  const int t   = threadIdx.x;

  // ---- P0: u16[b][k] = bf16(sum_c controls[c][b][k])
  if (t < 128) {
    const int idx = bid * 128 + t;  // 32768 units
    const int b = idx >> 9;
    const int k = (idx & 511) * 4;
    float4 s = make_float4(0.f, 0.f, 0.f, 0.f);
#pragma unroll
    for (int c = 0; c < CC; ++c) {
      const float4 v = *reinterpret_cast<const float4*>(
          controls + ((size_t)c * BB + b) * DM + k);
      s.x += v.x; s.y += v.y; s.z += v.z; s.w += v.w;
    }
    short4v o = {f2bf(s.x), f2bf(s.y), f2bf(s.z), f2bf(s.w)};
    *reinterpret_cast<short4v*>(u16 + (size_t)b * DM + k) = o;
  }
  gridbar(bar, NBLK);

  // ---- P1: gemm1 (u16 x Wv -> part1), 2 units/block
  gemm_unit(u16, Wv, part1, bid, &lw[0][0][0]);
  asm volatile("s_waitcnt vmcnt(0) lgkmcnt(0)" ::: "memory");
  __builtin_amdgcn_sched_barrier(0);
  gemm_unit(u16, Wv, part1, bid + NBLK, &lw[0][0][0]);
  gridbar(bar, 2 * NBLK);

  // ---- P2: v16[b][e] = bf16(sum_kp part1 + 8*bv[e])
  if (t < 128) {
    const int idx = bid * 128 + t;
    const int b = idx >> 9;
    const int e = (idx & 511) * 4;
    const float4 bb = *reinterpret_cast<const float4*>(bv + e);
    float4 s = make_float4(8.f * bb.x, 8.f * bb.y, 8.f * bb.z, 8.f * bb.w);
#pragma unroll
    for (int kp = 0; kp < KP; ++kp) {
      const short4v p = *reinterpret_cast<const short4v*>(
          part1 + ((size_t)kp * BB + b) * DM + e);
      s.x += bf2f(p[0]); s.y += bf2f(p[1]);
      s.z += bf2f(p[2]); s.w += bf2f(p[3]);
    }
    short4v o = {f2bf(s.x), f2bf(s.y), f2bf(s.z), f2bf(s.w)};
    *reinterpret_cast<short4v*>(v16 + (size_t)b * DM + e) = o;
  }
  gridbar(bar, 3 * NBLK);

  // ---- P3: gemm2 (v16 x Wo -> part2), 2 units/block
  gemm_unit(v16, Wo, part2, bid, &lw[0][0][0]);
  asm volatile("s_waitcnt vmcnt(0) lgkmcnt(0)" ::: "memory");
  __builtin_amdgcn_sched_barrier(0);
  gemm_unit(v16, Wo, part2, bid + NBLK, &lw[0][0][0]);
  gridbar(bar, 4 * NBLK);

  // ---- P4: out[b][s][e] = seq + (sum_kp part2 + 8*bo), 2 units/block
  for (int u = bid; u < 512; u += NBLK) {
    const int b  = u >> 3;
    const int e  = (u & 7) * 256 + (t & 63) * 4;
    const int s0 = (t >> 6) * 8;
    const float4 bb = *reinterpret_cast<const float4*>(bo + e);
    float4 pv = make_float4(8.f * bb.x, 8.f * bb.y, 8.f * bb.z, 8.f * bb.w);
#pragma unroll
    for (int kp = 0; kp < KP; ++kp) {
      const short4v p = *reinterpret_cast<const short4v*>(
          part2 + ((size_t)kp * BB + b) * DM + e);
      pv.x += bf2f(p[0]); pv.y += bf2f(p[1]);
      pv.z += bf2f(p[2]); pv.w += bf2f(p[3]);
    }
    const size_t base = (size_t)b * SS * DM + e;
#pragma unroll
    for (int i = 0; i < 8; ++i) {
      const size_t off = base + (size_t)(s0 + i) * DM;
      const float4 qd = *reinterpret_cast<const float4*>(seq + off);
      *reinterpret_cast<float4*>(out + off) =
          make_float4(qd.x + pv.x, qd.y + pv.y, qd.z + pv.z, qd.w + pv.w);
    }
  }
}

extern "C" void kernel_launch(void* const* d_in, const int* in_sizes, int n_in,
                              void* d_out, int out_size, void* d_ws,
                              size_t ws_size, hipStream_t stream) {
  const float* seq      = (const float*)d_in[0];
  const float* controls = (const float*)d_in[1];
  // d_in[2..5] = Wq, bq, Wk, bk — mathematically unused (softmax over size-1 axis == 1)
  const float* Wv = (const float*)d_in[6];
  const float* bv = (const float*)d_in[7];
  const float* Wo = (const float*)d_in[8];
  const float* bo = (const float*)d_in[9];
  float* out = (float*)d_out;

  char* ws = (char*)d_ws;
  int*   bar   = (int*)(ws);                     // 4 KB zeroed per call
  short* u16   = (short*)(ws + (4ull << 10));    // 256 KB bf16 [64][2048]
  short* v16   = (short*)(ws + (512ull << 10));  // 256 KB bf16 [64][2048]
  short* part1 = (short*)(ws + (1ull << 20));    // 4 MB bf16 [16][64][2048]
  short* part2 = (short*)(ws + (6ull << 20));    // 4 MB bf16 [16][64][2048]

  hipMemsetAsync(bar, 0, 4096, stream);
  fused_all<<<NBLK, 256, 0, stream>>>(seq, controls, Wv, bv, Wo, bo, u16, v16,
                                      part1, part2, out, bar);
}

// Round 10
// 49.816 us; speedup vs baseline: 2.2679x; 2.2679x over previous
//
#include <hip/hip_runtime.h>
#include <hip/hip_bf16.h>

#define DM 2048
#define BB 64
#define SS 32
#define CC 8

typedef __attribute__((ext_vector_type(8))) short short8;
typedef __attribute__((ext_vector_type(4))) short short4v;
typedef __attribute__((ext_vector_type(4))) float f32x4;

static __device__ __forceinline__ short f2bf(float f) {
  union { __hip_bfloat16 h; short s; } u;
  u.h = __float2bfloat16(f);
  return u.s;
}

// K1: u16[b][k] = bf16(sum_c controls[c][b][k]).  grid 256 x 128
__global__ void k1_sum_bf16(const float* __restrict__ controls,
                            short* __restrict__ u16) {
  const int idx = blockIdx.x * 128 + threadIdx.x;  // 32768
  const int b = idx >> 9;
  const int k = (idx & 511) * 4;
  float4 s = make_float4(0.f, 0.f, 0.f, 0.f);
#pragma unroll
  for (int c = 0; c < CC; ++c) {
    const float4 v = *reinterpret_cast<const float4*>(
        controls + ((size_t)c * BB + b) * DM + k);
    s.x += v.x; s.y += v.y; s.z += v.z; s.w += v.w;
  }
  short4v o = {f2bf(s.x), f2bf(s.y), f2bf(s.z), f2bf(s.w)};
  *reinterpret_cast<short4v*>(u16 + (size_t)b * DM + k) = o;
}

// Full-K GEMM, no inter-block k-split (no partials / reduce kernels).
// C[b][e] = sum_k A[b][k] * W[e][k] + 8*bias[e]   (A bf16, W fp32)
// grid 256 = 64 e-blocks(32e) x 4 b-groups(16b). Block = 4 waves:
//   wave wv -> (esub = wv&1: 16 e-rows, kh = wv>>1: k-half 1024).
// Per wave: 8 chunks of k=128; W (8KB) and A (4KB) staged per chunk via
// global_load_lds into per-wave double buffers -> counted vmcnt(12)
// pipelines chunk c+1's 12 loads under chunk c's compute (all loop VMEM is
// ours, so the count is exact). XOR-swizzle (granule ^ row&7) on the global
// source, linear LDS dest (m104/m173); same XOR on ds_read -> 2-way (free).
// k-halves pair-reduced via LDS.
// EPI=0: store bf16 v16[b][e].  EPI=1: + seq -> out (fused k4 epilogue).
template <int EPI>
__global__ __launch_bounds__(256) void gemm_full(
    const short* __restrict__ abf, const float* __restrict__ w,
    const float* __restrict__ bias, short* __restrict__ vout,
    const float* __restrict__ seq, float* __restrict__ out) {
  __shared__ float lwW[4][2][16][128];  // 64 KB
  __shared__ short lwA[4][2][16][128];  // 32 KB
  __shared__ f32x4 red4[2][64];         // 2 KB
  __shared__ float ptt[16][32];         // 2 KB (EPI=1)

  const int t    = threadIdx.x;
  const int lane = t & 63;
  const int wv   = t >> 6;
  const int esub = wv & 1;
  const int kh   = wv >> 1;
  const int eb   = blockIdx.x >> 2;
  const int bg   = blockIdx.x & 3;
  const int e0   = eb * 32;
  const int b0   = bg * 16;
  const int ew   = e0 + esub * 16;  // wave's 16 W rows
  const int kb   = kh * 1024;      // wave's k-half

  const int wrl = lane >> 5, wg = lane & 31;  // W staging: 2 rows x 32 gran
  const int arl = lane >> 4, ag = lane & 15;  // A staging: 4 rows x 16 gran
  const int r = lane & 15, ksub = lane >> 4;  // compute mapping
  const int q = r & 7;

  auto issue = [&](int c, int bsel) {
    const int ck = kb + c * 128;
    float* wd = &lwW[wv][bsel][0][0];
    short* ad = &lwA[wv][bsel][0][0];
#pragma unroll
    for (int i = 0; i < 8; ++i) {
      const int row = 2 * i + wrl;
      const float* src =
          w + (size_t)(ew + row) * DM + ck + ((wg ^ (row & 7)) << 2);
      __builtin_amdgcn_global_load_lds(
          (const __attribute__((address_space(1))) void*)src,
          (__attribute__((address_space(3))) void*)(wd + i * 256), 16, 0, 0);
    }
#pragma unroll
    for (int i = 0; i < 4; ++i) {
      const int row = 4 * i + arl;
      const short* src =
          abf + (size_t)(b0 + row) * DM + ck + ((ag ^ (row & 7)) << 3);
      __builtin_amdgcn_global_load_lds(
          (const __attribute__((address_space(1))) void*)src,
          (__attribute__((address_space(3))) void*)(ad + i * 512), 16, 0, 0);
    }
  };

  f32x4 acc = {0.f, 0.f, 0.f, 0.f};
  issue(0, 0);
#pragma unroll
  for (int c = 0; c < 8; ++c) {
    if (c < 7) {
      issue(c + 1, (c + 1) & 1);
      asm volatile("s_waitcnt vmcnt(12)" ::: "memory");  // chunk c landed
    } else {
      asm volatile("s_waitcnt vmcnt(0)" ::: "memory");
    }
    __builtin_amdgcn_sched_barrier(0);
    const float* wb = &lwW[wv][c & 1][0][0];
    const short* ab = &lwA[wv][c & 1][0][0];
#pragma unroll
    for (int s = 0; s < 4; ++s) {
      const int glA = s * 4 + ksub;       // A logical 16B granule
      const int glW = s * 8 + ksub * 2;   // W logical 16B granule (lo)
      const short8 af = *reinterpret_cast<const short8*>(
          ab + r * 128 + ((glA ^ q) << 3));
      const float4 lo = *reinterpret_cast<const float4*>(
          wb + r * 128 + ((glW ^ q) << 2));
      const float4 hi = *reinterpret_cast<const float4*>(
          wb + r * 128 + (((glW + 1) ^ q) << 2));
      short8 bf;
      bf[0] = f2bf(lo.x); bf[1] = f2bf(lo.y);
      bf[2] = f2bf(lo.z); bf[3] = f2bf(lo.w);
      bf[4] = f2bf(hi.x); bf[5] = f2bf(hi.y);
      bf[6] = f2bf(hi.z); bf[7] = f2bf(hi.w);
      acc = __builtin_amdgcn_mfma_f32_16x16x32_bf16(af, bf, acc, 0, 0, 0);
    }
  }

  // ---- k-half pair reduction (waves 2,3 -> waves 0,1)
  if (kh == 1) red4[esub][lane] = acc;
  __syncthreads();
  if (kh == 0) {
    const f32x4 o = red4[esub][lane];
    acc += o;
    const float be = 8.f * bias[ew + r];
    // D: lane reg j -> b = b0 + ksub*4 + j, e = ew + r
    if (EPI == 0) {
#pragma unroll
      for (int j = 0; j < 4; ++j)
        vout[(size_t)(b0 + ksub * 4 + j) * DM + ew + r] = f2bf(acc[j] + be);
    } else {
#pragma unroll
      for (int j = 0; j < 4; ++j)
        ptt[ksub * 4 + j][esub * 16 + r] = acc[j] + be;
    }
  }

  if (EPI == 1) {
    __syncthreads();
    // out[b0+bl][s][e0+ef..+3] = seq + ptt[bl][ef..+3]
    const int sl = t >> 7;          // 0..1
    const int qq = t & 127;
    const int bl = qq >> 3;         // 0..15
    const int ef = (qq & 7) * 4;    // 0..28
    const float4 pv = *reinterpret_cast<const float4*>(&ptt[bl][ef]);
#pragma unroll
    for (int s2 = 0; s2 < 16; ++s2) {
      const int s = s2 * 2 + sl;
      const size_t off = ((size_t)(b0 + bl) * SS + s) * DM + e0 + ef;
      const float4 qd = *reinterpret_cast<const float4*>(seq + off);
      *reinterpret_cast<float4*>(out + off) =
          make_float4(qd.x + pv.x, qd.y + pv.y, qd.z + pv.z, qd.w + pv.w);
    }
  }
}

extern "C" void kernel_launch(void* const* d_in, const int* in_sizes, int n_in,
                              void* d_out, int out_size, void* d_ws,
                              size_t ws_size, hipStream_t stream) {
  const float* seq      = (const float*)d_in[0];
  const float* controls = (const float*)d_in[1];
  // d_in[2..5] = Wq, bq, Wk, bk — mathematically unused (softmax over size-1 axis == 1)
  const float* Wv = (const float*)d_in[6];
  const float* bv = (const float*)d_in[7];
  const float* Wo = (const float*)d_in[8];
  const float* bo = (const float*)d_in[9];
  float* out = (float*)d_out;

  char* ws = (char*)d_ws;
  short* u16 = (short*)(ws);                   // 256 KB bf16 [64][2048]
  short* v16 = (short*)(ws + (512ull << 10));  // 256 KB bf16 [64][2048]

  k1_sum_bf16<<<256, 128, 0, stream>>>(controls, u16);
  gemm_full<0><<<256, 256, 0, stream>>>(u16, Wv, bv, v16, nullptr, nullptr);
  gemm_full<1><<<256, 256, 0, stream>>>(v16, Wo, bo, nullptr, seq, out);
}

// Round 11
// 32.475 us; speedup vs baseline: 3.4789x; 1.5340x over previous
//
#include <hip/hip_runtime.h>
#include <hip/hip_bf16.h>

#define DM 2048
#define BB 64
#define SS 32
#define CC 8

typedef __attribute__((ext_vector_type(8))) short short8;
typedef __attribute__((ext_vector_type(4))) short short4v;
typedef __attribute__((ext_vector_type(4))) float f32x4;

static __device__ __forceinline__ short f2bf(float f) {
  union { __hip_bfloat16 h; short s; } u;
  u.h = __float2bfloat16(f);
  return u.s;
}

// K1: u16[b][k] = bf16(sum_c controls[c][b][k]).  grid 256 x 128
__global__ void k1_sum_bf16(const float* __restrict__ controls,
                            short* __restrict__ u16) {
  const int idx = blockIdx.x * 128 + threadIdx.x;  // 32768
  const int b = idx >> 9;
  const int k = (idx & 511) * 4;
  float4 s = make_float4(0.f, 0.f, 0.f, 0.f);
#pragma unroll
  for (int c = 0; c < CC; ++c) {
    const float4 v = *reinterpret_cast<const float4*>(
        controls + ((size_t)c * BB + b) * DM + k);
    s.x += v.x; s.y += v.y; s.z += v.z; s.w += v.w;
  }
  short4v o = {f2bf(s.x), f2bf(s.y), f2bf(s.z), f2bf(s.w)};
  *reinterpret_cast<short4v*>(u16 + (size_t)b * DM + k) = o;
}

// Full-K GEMM v2: C[b][e] = sum_k A[b][k]*W[e][k] + 8*bias[e]
// Tile 16e x 16b, full k. 4 waves = 4 k-quarters (512 k each), LDS-reduced.
// W: per-chunk (128k) 8KB staged via global_load_lds, double-buffered
//    (64 KB total); XOR-swizzled source (granule ^ row&7), linear dest,
//    same XOR on ds_read.
// A: per-chunk 4x short8 in double-buffered VGPRs (no LDS -> no lwA
//    conflicts, -32KB LDS). All loop VMEM is ours: counted vmcnt(12).
// Occupancy fix vs r10: 68 KB LDS -> 2 blocks/CU; grid 512 -> 2 waves/SIMD
// (r10 was 1 blk/CU, 1 wave/SIMD, latency-starved).
// Grid map: eb = bid&127, bg = bid>>7 -> 4 bg blocks of one eb are
// congruent mod 8 -> same XCD -> W read once per L2.
// EPI=0: store bf16 vout[b][e].  EPI=1: + seq -> out (fused epilogue).
template <int EPI>
__global__ __launch_bounds__(256, 2) void gemm_full(
    const short* __restrict__ abf, const float* __restrict__ w,
    const float* __restrict__ bias, short* __restrict__ vout,
    const float* __restrict__ seq, float* __restrict__ out) {
  __shared__ float lwW[4][2][16 * 128];  // 64 KB
  __shared__ f32x4 red[3][64];           // 3 KB
  __shared__ float ptt[16][16];          // 1 KB (EPI=1)

  const int t    = threadIdx.x;
  const int lane = t & 63;
  const int wv   = t >> 6;        // k-quarter
  const int eb   = blockIdx.x & 127;
  const int bg   = blockIdx.x >> 7;
  const int e0   = eb * 16;
  const int b0   = bg * 16;
  const int kq   = wv * 512;

  const int wrl = lane >> 5, wg = lane & 31;  // W staging: 2 rows x 32 gran
  const int r = lane & 15, ksub = lane >> 4;  // compute mapping
  const int q = r & 7;

  const short* abase = abf + (size_t)(b0 + r) * DM + kq + ksub * 8;

  short8 areg[2][4];
  f32x4 acc = {0.f, 0.f, 0.f, 0.f};

  // chunk 0 issue
  {
    float* wd = &lwW[wv][0][0];
#pragma unroll
    for (int i = 0; i < 8; ++i) {
      const int row = 2 * i + wrl;
      const float* src =
          w + (size_t)(e0 + row) * DM + kq + ((wg ^ (row & 7)) << 2);
      __builtin_amdgcn_global_load_lds(
          (const __attribute__((address_space(1))) void*)src,
          (__attribute__((address_space(3))) void*)(wd + i * 256), 16, 0, 0);
    }
#pragma unroll
    for (int s = 0; s < 4; ++s)
      areg[0][s] = *reinterpret_cast<const short8*>(abase + s * 32);
  }

#pragma unroll
  for (int c = 0; c < 4; ++c) {
    if (c < 3) {
      const int ck = (c + 1) * 128;
      float* wd = &lwW[wv][(c + 1) & 1][0];
#pragma unroll
      for (int i = 0; i < 8; ++i) {
        const int row = 2 * i + wrl;
        const float* src =
            w + (size_t)(e0 + row) * DM + kq + ck + ((wg ^ (row & 7)) << 2);
        __builtin_amdgcn_global_load_lds(
            (const __attribute__((address_space(1))) void*)src,
            (__attribute__((address_space(3))) void*)(wd + i * 256), 16, 0, 0);
      }
#pragma unroll
      for (int s = 0; s < 4; ++s)
        areg[(c + 1) & 1][s] =
            *reinterpret_cast<const short8*>(abase + ck + s * 32);
      asm volatile("s_waitcnt vmcnt(12)" ::: "memory");  // chunk c landed
    } else {
      asm volatile("s_waitcnt vmcnt(0)" ::: "memory");
    }
    __builtin_amdgcn_sched_barrier(0);

    const float* wb = &lwW[wv][c & 1][0];
#pragma unroll
    for (int s = 0; s < 4; ++s) {
      const int glW = s * 8 + ksub * 2;  // logical 16B granule (lo)
      const float4 lo = *reinterpret_cast<const float4*>(
          wb + r * 128 + ((glW ^ q) << 2));
      const float4 hi = *reinterpret_cast<const float4*>(
          wb + r * 128 + (((glW + 1) ^ q) << 2));
      short8 bf;
      bf[0] = f2bf(lo.x); bf[1] = f2bf(lo.y);
      bf[2] = f2bf(lo.z); bf[3] = f2bf(lo.w);
      bf[4] = f2bf(hi.x); bf[5] = f2bf(hi.y);
      bf[6] = f2bf(hi.z); bf[7] = f2bf(hi.w);
      acc = __builtin_amdgcn_mfma_f32_16x16x32_bf16(areg[c & 1][s], bf, acc,
                                                    0, 0, 0);
    }
  }

  // ---- k-quarter reduction (waves 1-3 -> wave 0)
  if (wv != 0) red[wv - 1][lane] = acc;
  __syncthreads();
  if (wv == 0) {
    acc += red[0][lane];
    acc += red[1][lane];
    acc += red[2][lane];
    const float be = 8.f * bias[e0 + r];
    // D: lane reg j -> b = b0 + ksub*4 + j, e = e0 + r
    if (EPI == 0) {
#pragma unroll
      for (int j = 0; j < 4; ++j)
        vout[(size_t)(b0 + ksub * 4 + j) * DM + e0 + r] = f2bf(acc[j] + be);
    } else {
#pragma unroll
      for (int j = 0; j < 4; ++j) ptt[ksub * 4 + j][r] = acc[j] + be;
    }
  }

  if (EPI == 1) {
    __syncthreads();
    // out[b0+bl][s][e0+ef..+3] = seq + ptt[bl][ef..+3]
    const int ef = (t & 3) * 4;
    const int sl = (t >> 2) & 3;
    const int bl = t >> 4;
    const float4 pv = *reinterpret_cast<const float4*>(&ptt[bl][ef]);
#pragma unroll
    for (int i = 0; i < 8; ++i) {
      const int s = sl + i * 4;
      const size_t off = ((size_t)(b0 + bl) * SS + s) * DM + e0 + ef;
      const float4 qd = *reinterpret_cast<const float4*>(seq + off);
      *reinterpret_cast<float4*>(out + off) =
          make_float4(qd.x + pv.x, qd.y + pv.y, qd.z + pv.z, qd.w + pv.w);
    }
  }
}

extern "C" void kernel_launch(void* const* d_in, const int* in_sizes, int n_in,
                              void* d_out, int out_size, void* d_ws,
                              size_t ws_size, hipStream_t stream) {
  const float* seq      = (const float*)d_in[0];
  const float* controls = (const float*)d_in[1];
  // d_in[2..5] = Wq, bq, Wk, bk — mathematically unused (softmax over size-1 axis == 1)
  const float* Wv = (const float*)d_in[6];
  const float* bv = (const float*)d_in[7];
  const float* Wo = (const float*)d_in[8];
  const float* bo = (const float*)d_in[9];
  float* out = (float*)d_out;

  char* ws = (char*)d_ws;
  short* u16 = (short*)(ws);                   // 256 KB bf16 [64][2048]
  short* v16 = (short*)(ws + (512ull << 10));  // 256 KB bf16 [64][2048]

  k1_sum_bf16<<<256, 128, 0, stream>>>(controls, u16);
  gemm_full<0><<<512, 256, 0, stream>>>(u16, Wv, bv, v16, nullptr, nullptr);
  gemm_full<1><<<512, 256, 0, stream>>>(v16, Wo, bo, nullptr, seq, out);
}